// Round 1
// 106.061 us; speedup vs baseline: 1.0060x; 1.0060x over previous
//
#include <hip/hip_runtime.h>

typedef unsigned short u16;
typedef unsigned int u32;
typedef __attribute__((ext_vector_type(2))) _Float16 h2;   // packed f16 pair (v_pk_fma_f16)
typedef __attribute__((ext_vector_type(8))) _Float16 h8;   // MFMA f16 A/B frag
typedef __attribute__((ext_vector_type(4))) float f32x4;   // MFMA C/D frag

#define BLOCK 128        // one tile (16 outputs) per block; 2 k-half waves

__device__ __forceinline__ u16 f2h(float f) {   // RNE f32 -> f16
    union { _Float16 h; u16 u; } v; v.h = (_Float16)f; return v.u;
}

// prep: (a) feats f32 -> f16 rows (halves gather traffic vs f32);
//       (b) kmat -> ready-made MFMA B-fragment image (f16)
__global__ __launch_bounds__(256)
void prep_all(const float* __restrict__ feats, const float* __restrict__ kmat,
              u16* __restrict__ fh, u16* __restrict__ kbg, int n8) {
    const int id = blockIdx.x * 256 + threadIdx.x;
    if (id < n8) {
        const float4 a = ((const float4*)feats)[2 * id];
        const float4 b = ((const float4*)feats)[2 * id + 1];
        union { u16 h[8]; int4 v; } p;
        p.h[0] = f2h(a.x); p.h[1] = f2h(a.y); p.h[2] = f2h(a.z); p.h[3] = f2h(a.w);
        p.h[4] = f2h(b.x); p.h[5] = f2h(b.y); p.h[6] = f2h(b.z); p.h[7] = f2h(b.w);
        ((int4*)fh)[id] = p.v;
    }
    if (id < 16384) {
        const int k = id >> 6, n = id & 63;       // kmat flat = [k][n]
        const int kstep = k >> 5, quad = (k >> 3) & 3, j = k & 7;
        const int ntile = n >> 4, lanep = (quad << 4) | (n & 15);
        kbg[((((ntile << 3) | kstep) << 6) | lanep) * 8 + j] = f2h(kmat[id]);
    }
}

// R16 = R15 (best: 106.7 us) with the whole datapath moved bf16 -> f16:
//   A1: 256 (m,t) slots over 128 threads -> duplicated f16 sph pairs + idx in LDS
//       [t][m] (+1 pad on middle dim: kills the 16-way column-write bank conflict)
//   A2: gathered uint4 (8 f16) feeds v_pk_fma_f16 DIRECTLY (no bf16 unpack);
//       acc stays f16x2 -> acc2[s][0..3] IS the mfma A-frag (zero pack epilogue)
//   B : 4 nt x 4 ks mfma_f32_16x16x32_f16; B-frags from global f16 kbg image
//   Red: kh=1 writes C (4 KB LDS); kh=0 sums + bias + stores. 2 barriers.
template<bool WS>
__global__ __launch_bounds__(BLOCK)
void sphconv_tile(const float* __restrict__ featsf,   // [N_IN, 64] f32
                  const u16* __restrict__ fh,         // [N_IN, 64] f16 (d_ws)
                  const u16* __restrict__ kbg,        // B-frag image f16 (d_ws)
                  const float* __restrict__ in_pos,   // [N_IN, 3]
                  const float* __restrict__ out_pos,  // [N_OUT, 3]
                  const float* __restrict__ extents,  // [1]
                  const float* __restrict__ kmat,     // [4,64,64] = [k=256][f=64]
                  const float* __restrict__ bias,     // [64]
                  const int* __restrict__ nidx,       // [E]
                  const int* __restrict__ rsplits,    // [N_OUT+1]
                  float* __restrict__ out,            // [N_OUT,64]
                  int n_out, int n_edges)
{
    __shared__ __align__(16) _Float16 sphT[16][17][8]; // [t][m][s-pairs] 4.25 KB (+pad)
    __shared__ int      idxT[16][17];                  // [t][m]          1.06 KB (+pad)
    __shared__ __align__(16) float redT[4][64][4];     // [nt][lane]      4 KB

    const int tid = threadIdx.x;
    const int kh  = tid >> 6;                 // wave = k-half (c-half)
    const int lane = tid & 63;
    const int m = lane & 15, quad = lane >> 4;
    const int obase = blockIdx.x << 4;

    const float inv_ext = __fdividef(1.f, extents[0]);

    // ---- A1: tile's 256 (m,t) slots over 128 threads, 2 per thread ----
    #pragma unroll
    for (int u = 0; u < 2; ++u) {
        const int slot = (u << 7) | tid;      // 0..255, lane-contiguous
        const int mm = slot >> 4, t = slot & 15;
        const int o  = obase + mm;
        const int oc = min(o, n_out - 1);
        const int e0 = rsplits[oc], e1 = rsplits[oc + 1];
        const int e  = e0 + t;
        const bool v = (o < n_out) && (e < e1);
        const int id = nidx[min(e, n_edges - 1)];     // coalesced (e ~ slot)
        const float dx = in_pos[id * 3 + 0] - out_pos[oc * 3 + 0];
        const float dy = in_pos[id * 3 + 1] - out_pos[oc * 3 + 1];
        const float dz = in_pos[id * 3 + 2] - out_pos[oc * 3 + 2];
        const float rp2 = dx * dx + dy * dy;
        const float r2  = rp2 + dz * dz;
        const float rs  = fmaxf(sqrtf(r2), 1e-10f);
        const float rp  = fmaxf(sqrtf(rp2), 1e-10f);
        const float ir  = __fdividef(1.f, rs);
        const float irp = __fdividef(1.f, rp);
        const _Float16 w0 = (_Float16)(v ? rs * inv_ext : 0.f);
        const _Float16 w1 = (_Float16)(v ? dz * ir      : 0.f);
        const _Float16 w2 = (_Float16)(v ? dy * irp     : 0.f);
        const _Float16 w3 = (_Float16)(v ? dx * irp     : 0.f);
        union { _Float16 hh[8]; uint4 v4; } pk;       // duplicated pairs {w,w}
        pk.hh[0] = w0; pk.hh[1] = w0;
        pk.hh[2] = w1; pk.hh[3] = w1;
        pk.hh[4] = w2; pk.hh[5] = w2;
        pk.hh[6] = w3; pk.hh[7] = w3;
        idxT[t][mm] = id;
        *(uint4*)&sphT[t][mm][0] = pk.v4;
    }
    __syncthreads();

    // ---- A2: packed-f16 accumulation (gathered words used as-is) ----
    h2 acc2[4][4];
    #pragma unroll
    for (int s = 0; s < 4; ++s)
        #pragma unroll
        for (int p = 0; p < 4; ++p) acc2[s][p] = (h2)(_Float16)0.f;

    #pragma unroll 8
    for (int t = 0; t < 16; ++t) {
        const int idx = idxT[t][m];                   // broadcast across quads
        union { uint4 v4; h2 h[4]; } sp;
        sp.v4 = *(const uint4*)&sphT[t][m][0];        // 4 dup'd sph pairs
        union { uint4 v4; h2 h[4]; } fw;
        if constexpr (WS) {
            fw.v4 = *(const uint4*)(fh + (idx << 6) + (kh << 5) + (quad << 3));
        } else {
            const float* fr = featsf + (idx << 6) + (kh << 5) + (quad << 3);
            const float4 a0 = *(const float4*)fr;
            const float4 a1 = *(const float4*)(fr + 4);
            fw.h[0] = (h2){(_Float16)a0.x, (_Float16)a0.y};
            fw.h[1] = (h2){(_Float16)a0.z, (_Float16)a0.w};
            fw.h[2] = (h2){(_Float16)a1.x, (_Float16)a1.y};
            fw.h[3] = (h2){(_Float16)a1.z, (_Float16)a1.w};
        }
        #pragma unroll
        for (int s = 0; s < 4; ++s) {
            const h2 ws = sp.h[s];
            #pragma unroll
            for (int p = 0; p < 4; ++p)
                acc2[s][p] = fw.h[p] * ws + acc2[s][p];   // v_pk_fma_f16
        }
    }

    // ---- A-frags: acc2[s][0..3] concatenated IS the frag (register bitcast) ----
    h8 afr[4];
    #pragma unroll
    for (int s = 0; s < 4; ++s) {
        union { h2 h[4]; h8 v; } u;
        #pragma unroll
        for (int p = 0; p < 4; ++p) u.h[p] = acc2[s][p];
        afr[s] = u.v;
    }

    // ---- B: 4 nt x 4 ks MFMA; B-frags from global (coalesced 1 KB loads) ----
    f32x4 C[4] = {{0,0,0,0},{0,0,0,0},{0,0,0,0},{0,0,0,0}};
    #pragma unroll
    for (int nt = 0; nt < 4; ++nt) {
        h8 b[4];
        #pragma unroll
        for (int s = 0; s < 4; ++s) {
            const int ks = (s << 1) | kh;
            if constexpr (WS) {
                b[s] = *(const h8*)(kbg + ((((nt << 3) | ks) << 6) | lane) * 8);
            } else {
                union { u16 hh[8]; h8 v; } p;
                #pragma unroll
                for (int j = 0; j < 8; ++j) {
                    const int k = (ks << 5) | (quad << 3) | j;
                    const int n = (nt << 4) | m;
                    p.hh[j] = f2h(kmat[k * 64 + n]);
                }
                b[s] = p.v;
            }
        }
        #pragma unroll
        for (int s = 0; s < 4; ++s)
            C[nt] = __builtin_amdgcn_mfma_f32_16x16x32_f16(afr[s], b[s], C[nt], 0, 0, 0);
    }

    // ---- pair reduction + epilogue ----
    if (kh == 1) {
        #pragma unroll
        for (int nt = 0; nt < 4; ++nt)
            *(f32x4*)&redT[nt][lane][0] = C[nt];      // ds_write_b128, dense
    }
    __syncthreads();
    if (kh == 0) {
        #pragma unroll
        for (int nt = 0; nt < 4; ++nt) {
            const f32x4 P = *(const f32x4*)&redT[nt][lane][0];
            const int f = (nt << 4) | m;              // D: n = lane&15
            const float bv = bias[f];
            #pragma unroll
            for (int r = 0; r < 4; ++r) {
                const int oo = obase + (quad << 2) + r;   // D: m = quad*4 + r
                if (oo < n_out) out[(oo << 6) | f] = C[nt][r] + P[r] + bv;
            }
        }
    }
}

extern "C" void kernel_launch(void* const* d_in, const int* in_sizes, int n_in,
                              void* d_out, int out_size, void* d_ws, size_t ws_size,
                              hipStream_t stream) {
    const float* feats   = (const float*)d_in[0];
    const float* in_pos  = (const float*)d_in[1];
    const float* out_pos = (const float*)d_in[2];
    const float* extents = (const float*)d_in[3];
    const float* kmat    = (const float*)d_in[4];
    const float* bias    = (const float*)d_in[5];
    const int*   nidx    = (const int*)d_in[6];
    const int*   rsplits = (const int*)d_in[7];
    const int n_out   = in_sizes[7] - 1;
    const int n_edges = in_sizes[6];
    const int ntiles  = (n_out + 15) >> 4;

    const size_t fh_bytes = (size_t)in_sizes[0] * 2;
    const size_t need = fh_bytes + 32768;
    if (ws_size >= need && (in_sizes[0] & 7) == 0) {
        u16* fh  = (u16*)d_ws;
        u16* kbg = (u16*)((char*)d_ws + fh_bytes);
        const int n8 = in_sizes[0] / 8;
        const int pmax = n8 > 16384 ? n8 : 16384;
        prep_all<<<(pmax + 255) / 256, 256, 0, stream>>>(feats, kmat, fh, kbg, n8);
        sphconv_tile<true><<<ntiles, BLOCK, 0, stream>>>(
            feats, fh, kbg, in_pos, out_pos, extents, kmat, bias, nidx, rsplits,
            (float*)d_out, n_out, n_edges);
    } else {
        sphconv_tile<false><<<ntiles, BLOCK, 0, stream>>>(
            feats, nullptr, nullptr, in_pos, out_pos, extents, kmat, bias, nidx, rsplits,
            (float*)d_out, n_out, n_edges);
    }
}

// Round 2
// 104.041 us; speedup vs baseline: 1.0255x; 1.0194x over previous
//
#include <hip/hip_runtime.h>

typedef unsigned short u16;
typedef unsigned int u32;
typedef __attribute__((ext_vector_type(2))) _Float16 h2;   // packed f16 pair (v_pk_fma_f16)
typedef __attribute__((ext_vector_type(8))) _Float16 h8;   // MFMA f16 A/B frag
typedef __attribute__((ext_vector_type(4))) float f32x4;   // MFMA C/D frag

#define BLOCK 128        // one tile (16 outputs) per block; 2 k-half waves

__device__ __forceinline__ u16 f2h(float f) {   // RNE f32 -> f16
    union { _Float16 h; u16 u; } v; v.h = (_Float16)f; return v.u;
}

// prep: (a) feats f32 -> f16 rows (halves gather traffic vs f32);
//       (b) kmat -> ready-made MFMA B-fragment image (f16)
__global__ __launch_bounds__(256)
void prep_all(const float* __restrict__ feats, const float* __restrict__ kmat,
              u16* __restrict__ fh, u16* __restrict__ kbg, int n8) {
    const int id = blockIdx.x * 256 + threadIdx.x;
    if (id < n8) {
        const float4 a = ((const float4*)feats)[2 * id];
        const float4 b = ((const float4*)feats)[2 * id + 1];
        union { u16 h[8]; int4 v; } p;
        p.h[0] = f2h(a.x); p.h[1] = f2h(a.y); p.h[2] = f2h(a.z); p.h[3] = f2h(a.w);
        p.h[4] = f2h(b.x); p.h[5] = f2h(b.y); p.h[6] = f2h(b.z); p.h[7] = f2h(b.w);
        ((int4*)fh)[id] = p.v;
    }
    if (id < 16384) {
        const int k = id >> 6, n = id & 63;       // kmat flat = [k][n]
        const int kstep = k >> 5, quad = (k >> 3) & 3, j = k & 7;
        const int ntile = n >> 4, lanep = (quad << 4) | (n & 15);
        kbg[((((ntile << 3) | kstep) << 6) | lanep) * 8 + j] = f2h(kmat[id]);
    }
}

// R17 = R16 (106.06 us) + occupancy push:
//   __launch_bounds__(128,8): target <=64 VGPR -> 8 waves/SIMD (was ~4).
//   A2 unroll 2 (in-flight gather regs 32->12; TLP replaces ILP at 8 w/SIMD).
//   A1 via v_rsq (2 rsq replace 2 sqrt + 2 rcp per slot; fewer live temps).
//   Rest identical: f16 datapath, dup'd sph pairs, MFMA 16x16x32_f16,
//   kh=1 -> redT -> kh=0 reduction, 2 barriers.
template<bool WS>
__global__ __launch_bounds__(BLOCK, 8)
void sphconv_tile(const float* __restrict__ featsf,   // [N_IN, 64] f32
                  const u16* __restrict__ fh,         // [N_IN, 64] f16 (d_ws)
                  const u16* __restrict__ kbg,        // B-frag image f16 (d_ws)
                  const float* __restrict__ in_pos,   // [N_IN, 3]
                  const float* __restrict__ out_pos,  // [N_OUT, 3]
                  const float* __restrict__ extents,  // [1]
                  const float* __restrict__ kmat,     // [4,64,64] = [k=256][f=64]
                  const float* __restrict__ bias,     // [64]
                  const int* __restrict__ nidx,       // [E]
                  const int* __restrict__ rsplits,    // [N_OUT+1]
                  float* __restrict__ out,            // [N_OUT,64]
                  int n_out, int n_edges)
{
    __shared__ __align__(16) _Float16 sphT[16][17][8]; // [t][m][s-pairs] 4.25 KB (+pad)
    __shared__ int      idxT[16][17];                  // [t][m]          1.06 KB (+pad)
    __shared__ __align__(16) float redT[4][64][4];     // [nt][lane]      4 KB

    const int tid = threadIdx.x;
    const int kh  = tid >> 6;                 // wave = k-half (c-half)
    const int lane = tid & 63;
    const int m = lane & 15, quad = lane >> 4;
    const int obase = blockIdx.x << 4;

    const float inv_ext = __fdividef(1.f, extents[0]);

    // ---- A1: tile's 256 (m,t) slots over 128 threads, 2 per thread ----
    #pragma unroll
    for (int u = 0; u < 2; ++u) {
        const int slot = (u << 7) | tid;      // 0..255, lane-contiguous
        const int mm = slot >> 4, t = slot & 15;
        const int o  = obase + mm;
        const int oc = min(o, n_out - 1);
        const int e0 = rsplits[oc], e1 = rsplits[oc + 1];
        const int e  = e0 + t;
        const bool v = (o < n_out) && (e < e1);
        const int id = nidx[min(e, n_edges - 1)];     // coalesced (e ~ slot)
        const float dx = in_pos[id * 3 + 0] - out_pos[oc * 3 + 0];
        const float dy = in_pos[id * 3 + 1] - out_pos[oc * 3 + 1];
        const float dz = in_pos[id * 3 + 2] - out_pos[oc * 3 + 2];
        const float rp2 = dx * dx + dy * dy;
        const float r2  = rp2 + dz * dz;
        // v_rsq path: ir == 1/max(sqrt(r2),1e-10) for all r2 >= 1e-20 (clamped);
        // rs == max(sqrt(r2),1e-10) within f16 rounding (sub-1e-10 radii -> 0 in f16)
        const float ir  = __builtin_amdgcn_rsqf(fmaxf(r2,  1e-20f));
        const float irp = __builtin_amdgcn_rsqf(fmaxf(rp2, 1e-20f));
        const float rs  = r2 * ir;
        const _Float16 w0 = (_Float16)(v ? rs * inv_ext : 0.f);
        const _Float16 w1 = (_Float16)(v ? dz * ir      : 0.f);
        const _Float16 w2 = (_Float16)(v ? dy * irp     : 0.f);
        const _Float16 w3 = (_Float16)(v ? dx * irp     : 0.f);
        union { _Float16 hh[8]; uint4 v4; } pk;       // duplicated pairs {w,w}
        pk.hh[0] = w0; pk.hh[1] = w0;
        pk.hh[2] = w1; pk.hh[3] = w1;
        pk.hh[4] = w2; pk.hh[5] = w2;
        pk.hh[6] = w3; pk.hh[7] = w3;
        idxT[t][mm] = id;
        *(uint4*)&sphT[t][mm][0] = pk.v4;
    }
    __syncthreads();

    // ---- A2: packed-f16 accumulation (gathered words used as-is) ----
    h2 acc2[4][4];
    #pragma unroll
    for (int s = 0; s < 4; ++s)
        #pragma unroll
        for (int p = 0; p < 4; ++p) acc2[s][p] = (h2)(_Float16)0.f;

    const u16* __restrict__ fbase = fh + (kh << 5) + (quad << 3);
    const float* __restrict__ ffbase = featsf + (kh << 5) + (quad << 3);

    #pragma unroll 2
    for (int t = 0; t < 16; ++t) {
        const int idx = idxT[t][m];                   // broadcast across quads
        union { uint4 v4; h2 h[4]; } sp;
        sp.v4 = *(const uint4*)&sphT[t][m][0];        // 4 dup'd sph pairs
        union { uint4 v4; h2 h[4]; } fw;
        if constexpr (WS) {
            fw.v4 = *(const uint4*)(fbase + (idx << 6));
        } else {
            const float* fr = ffbase + (idx << 6);
            const float4 a0 = *(const float4*)fr;
            const float4 a1 = *(const float4*)(fr + 4);
            fw.h[0] = (h2){(_Float16)a0.x, (_Float16)a0.y};
            fw.h[1] = (h2){(_Float16)a0.z, (_Float16)a0.w};
            fw.h[2] = (h2){(_Float16)a1.x, (_Float16)a1.y};
            fw.h[3] = (h2){(_Float16)a1.z, (_Float16)a1.w};
        }
        #pragma unroll
        for (int s = 0; s < 4; ++s) {
            const h2 ws = sp.h[s];
            #pragma unroll
            for (int p = 0; p < 4; ++p)
                acc2[s][p] = fw.h[p] * ws + acc2[s][p];   // v_pk_fma_f16
        }
    }

    // ---- A-frags: acc2[s][0..3] concatenated IS the frag (register bitcast) ----
    h8 afr[4];
    #pragma unroll
    for (int s = 0; s < 4; ++s) {
        union { h2 h[4]; h8 v; } u;
        #pragma unroll
        for (int p = 0; p < 4; ++p) u.h[p] = acc2[s][p];
        afr[s] = u.v;
    }

    // ---- B: 4 nt x 4 ks MFMA; B-frags from global (coalesced 1 KB loads) ----
    f32x4 C[4] = {{0,0,0,0},{0,0,0,0},{0,0,0,0},{0,0,0,0}};
    #pragma unroll
    for (int nt = 0; nt < 4; ++nt) {
        h8 b[4];
        #pragma unroll
        for (int s = 0; s < 4; ++s) {
            const int ks = (s << 1) | kh;
            if constexpr (WS) {
                b[s] = *(const h8*)(kbg + ((((nt << 3) | ks) << 6) | lane) * 8);
            } else {
                union { u16 hh[8]; h8 v; } p;
                #pragma unroll
                for (int j = 0; j < 8; ++j) {
                    const int k = (ks << 5) | (quad << 3) | j;
                    const int n = (nt << 4) | m;
                    p.hh[j] = f2h(kmat[k * 64 + n]);
                }
                b[s] = p.v;
            }
        }
        #pragma unroll
        for (int s = 0; s < 4; ++s)
            C[nt] = __builtin_amdgcn_mfma_f32_16x16x32_f16(afr[s], b[s], C[nt], 0, 0, 0);
    }

    // ---- pair reduction + epilogue ----
    if (kh == 1) {
        #pragma unroll
        for (int nt = 0; nt < 4; ++nt)
            *(f32x4*)&redT[nt][lane][0] = C[nt];      // ds_write_b128, dense
    }
    __syncthreads();
    if (kh == 0) {
        #pragma unroll
        for (int nt = 0; nt < 4; ++nt) {
            const f32x4 P = *(const f32x4*)&redT[nt][lane][0];
            const int f = (nt << 4) | m;              // D: n = lane&15
            const float bv = bias[f];
            #pragma unroll
            for (int r = 0; r < 4; ++r) {
                const int oo = obase + (quad << 2) + r;   // D: m = quad*4 + r
                if (oo < n_out) out[(oo << 6) | f] = C[nt][r] + P[r] + bv;
            }
        }
    }
}

extern "C" void kernel_launch(void* const* d_in, const int* in_sizes, int n_in,
                              void* d_out, int out_size, void* d_ws, size_t ws_size,
                              hipStream_t stream) {
    const float* feats   = (const float*)d_in[0];
    const float* in_pos  = (const float*)d_in[1];
    const float* out_pos = (const float*)d_in[2];
    const float* extents = (const float*)d_in[3];
    const float* kmat    = (const float*)d_in[4];
    const float* bias    = (const float*)d_in[5];
    const int*   nidx    = (const int*)d_in[6];
    const int*   rsplits = (const int*)d_in[7];
    const int n_out   = in_sizes[7] - 1;
    const int n_edges = in_sizes[6];
    const int ntiles  = (n_out + 15) >> 4;

    const size_t fh_bytes = (size_t)in_sizes[0] * 2;
    const size_t need = fh_bytes + 32768;
    if (ws_size >= need && (in_sizes[0] & 7) == 0) {
        u16* fh  = (u16*)d_ws;
        u16* kbg = (u16*)((char*)d_ws + fh_bytes);
        const int n8 = in_sizes[0] / 8;
        const int pmax = n8 > 16384 ? n8 : 16384;
        prep_all<<<(pmax + 255) / 256, 256, 0, stream>>>(feats, kmat, fh, kbg, n8);
        sphconv_tile<true><<<ntiles, BLOCK, 0, stream>>>(
            feats, fh, kbg, in_pos, out_pos, extents, kmat, bias, nidx, rsplits,
            (float*)d_out, n_out, n_edges);
    } else {
        sphconv_tile<false><<<ntiles, BLOCK, 0, stream>>>(
            feats, nullptr, nullptr, in_pos, out_pos, extents, kmat, bias, nidx, rsplits,
            (float*)d_out, n_out, n_edges);
    }
}